// Round 18
// baseline (541.115 us; speedup 1.0000x reference)
//
#include <hip/hip_runtime.h>
#include <stdint.h>

#define B_SZ 8192
#define D_SZ 1024
#define H_SZ 4096
#define O_SZ 1000

#define MARGIN 0.0625f

typedef float f32x4 __attribute__((ext_vector_type(4)));
typedef __bf16 bf16x8 __attribute__((ext_vector_type(8)));

// ---------------- fp32 -> bf16 (round-to-nearest-even) ----------------
static __device__ __forceinline__ uint16_t f2bf(float f) {
  uint32_t u = __float_as_uint(f);
  uint32_t r = (u + 0x7fffu + ((u >> 16) & 1u)) >> 16;
  return (uint16_t)r;
}

// ---------------- fused prep: x->bf16 | w->bf16 + w2(f64) ----------------
__global__ __launch_bounds__(256) void prep(const float* __restrict__ x,
                                            uint16_t* __restrict__ xb,
                                            const float* __restrict__ w,
                                            uint16_t* __restrict__ wb,
                                            double* __restrict__ w2d) {
  const int bid = blockIdx.x;
  const int tid = threadIdx.x;
  if (bid < 8192) {
    const int i = bid * 256 + tid;
    f32x4 v = reinterpret_cast<const f32x4*>(x)[i];
    ushort4 o;
    o.x = f2bf(v[0]); o.y = f2bf(v[1]); o.z = f2bf(v[2]); o.w = f2bf(v[3]);
    reinterpret_cast<ushort4*>(xb)[i] = o;
  } else {
    const int h = (bid - 8192) * 4 + (tid >> 6);  // [0, 4096)
    const int l = tid & 63;
    const f32x4* wr = reinterpret_cast<const f32x4*>(w + (size_t)h * D_SZ);
    ushort4* wo = reinterpret_cast<ushort4*>(wb + (size_t)h * D_SZ);
    double s = 0.0;
#pragma unroll
    for (int j = 0; j < 4; ++j) {
      f32x4 v = wr[j * 64 + l];
      s += (double)v[0] * v[0] + (double)v[1] * v[1] + (double)v[2] * v[2] + (double)v[3] * v[3];
      ushort4 o;
      o.x = f2bf(v[0]); o.y = f2bf(v[1]); o.z = f2bf(v[2]); o.w = f2bf(v[3]);
      wo[j * 64 + l] = o;
    }
#pragma unroll
    for (int m = 32; m; m >>= 1) s += __shfl_xor(s, m);
    if (l == 0) w2d[h] = s;
  }
}

// ---------------- phase 1: 256x256 bf16 MFMA GEMM — BK=32, 64KB LDS, 2 blocks/CU --------
// R18 experiment: same read/MFMA ratio as the verified R14 schedule (12 reads / 32 MFMA
// per K-tile/wave vs 24/64) but LDS halved to 64 KB -> TWO blocks resident per CU.
// Mechanism (m114): the second block's waves fill the first block's barrier/vmcnt stalls;
// per-CU cost goes from LDS+MFMA serialized (~181k cyc measured) toward max(LDS,MFMA).
// Slots (8 KB each): A-slot a = matrix rows {a*64..+63} u {128+a*64..+63};
//                    B-slot b = rows (sr>>5)*64 + b*32 + (sr&31). 32 K-tiles of 32.
// Swizzle (64B rows, derived 8-distinct-quad): read byte ^= ((r15>>1)&3)<<4;
//   glds source chunk pp = lp ^ ((lr>>1)&3) (linear LDS dest, rule #21 both-sides).
// Waits (FIFO-derived; stages per tile in order a0@ph0,b0@ph1,b1@ph2,a1@ph3, 1 glds each):
//   ph0: reads a0,b0 (covered by prev ph3 vmcnt(2)); stage a0'; vmcnt(2) retires b1
//   ph1: reads b1    (covered by ph0);               stage b0'; vmcnt(2) retires a1
//   ph2: reads a1    (covered by ph1);               stage b1'; (no wait needed)
//   ph3: no reads;                                   stage a1'; vmcnt(2) retires a0',b0'
// Every wait targets loads issued >=2 phases earlier. t==31: vmcnt(0) at ph0 drains.
// Overwrite safety: each sp-slot stage is >=4 barriers after that slot's last rp-read.
__global__ __launch_bounds__(512, 4) void kohonen_gemm256(const uint16_t* __restrict__ xb,
                                                          const uint16_t* __restrict__ wb,
                                                          float* __restrict__ tmax64,
                                                          unsigned long long* __restrict__ tmask64) {
  extern __shared__ char smem[];  // 65536 B: A slots @0 (4x8KB), B slots @32768
  const int tid = threadIdx.x;
  const int lane = tid & 63, wid = tid >> 6;
  const int wm = wid >> 2, wn = wid & 3;
  const int r15 = lane & 15, g = lane >> 4;
  const int xorv = ((r15 >> 1) & 3) << 4;   // 64B-row chunk swizzle (read side)
  const int lr = lane >> 2, lp = lane & 3;  // staging: row-within-16, 16B chunk

  // XCD-bijective swizzle: 512 blocks = 8 XCDs x 64
  const int bid = blockIdx.x;
  const int wg = (bid & 7) * 64 + (bid >> 3);
  const int bm = wg >> 4, bn = wg & 15;

  const uint16_t* xrow = xb + (size_t)(bm * 256) * D_SZ;
  const uint16_t* wrow = wb + (size_t)(bn * 256) * D_SZ;

  f32x4 acc[8][4] = {};
  bf16x8 Af[4];      // current qm-half of A: [mi]
  bf16x8 Bf[2][2];   // both qn-halves of B: [qn][ni]

  auto stage_a = [&](int a, int sp, int kt) {
    const int sr = wid * 16 + lr;            // slot-row [0,128)
    const int pp = lp ^ ((lr >> 1) & 3);     // pre-swizzled source chunk
    const int mr = (sr < 64) ? (a * 64 + sr) : (128 + a * 64 + (sr - 64));
    const uint16_t* src = xrow + (size_t)mr * D_SZ + kt * 32 + pp * 8;
    __builtin_amdgcn_global_load_lds(
        (const __attribute__((address_space(1))) uint32_t*)src,
        (__attribute__((address_space(3))) uint32_t*)(smem + (sp * 2 + a) * 8192 + wid * 1024),
        16, 0, 0);
  };
  auto stage_b = [&](int b, int sp, int kt) {
    const int sr = wid * 16 + lr;
    const int pp = lp ^ ((lr >> 1) & 3);
    const int mr = (sr >> 5) * 64 + b * 32 + (sr & 31);
    const uint16_t* src = wrow + (size_t)mr * D_SZ + kt * 32 + pp * 8;
    __builtin_amdgcn_global_load_lds(
        (const __attribute__((address_space(1))) uint32_t*)src,
        (__attribute__((address_space(3))) uint32_t*)(smem + 32768 + (sp * 2 + b) * 8192 +
                                                      wid * 1024),
        16, 0, 0);
  };

#define LDA(QM)                                                                  \
  {                                                                              \
    const char* Abq = smem + rp * 16384 + (QM)*8192;                             \
    _Pragma("unroll") for (int mi = 0; mi < 4; ++mi) {                           \
      const int sr = wm * 64 + mi * 16 + r15;                                    \
      Af[mi] = *reinterpret_cast<const bf16x8*>(Abq + ((sr * 64 + g * 16) ^ xorv)); \
    }                                                                            \
  }
#define LDB(QN)                                                                  \
  {                                                                              \
    const char* Bbq = smem + 32768 + rp * 16384 + (QN)*8192;                     \
    _Pragma("unroll") for (int ni = 0; ni < 2; ++ni) {                           \
      const int sr = wn * 32 + ni * 16 + r15;                                    \
      Bf[QN][ni] = *reinterpret_cast<const bf16x8*>(Bbq + ((sr * 64 + g * 16) ^ xorv)); \
    }                                                                            \
  }
#define MFMAQ(QM, QN)                                                            \
  __builtin_amdgcn_s_setprio(1);                                                 \
  _Pragma("unroll") for (int mi = 0; mi < 4; ++mi)                               \
      _Pragma("unroll") for (int ni = 0; ni < 2; ++ni)                           \
          acc[(QM)*4 + mi][(QN)*2 + ni] = __builtin_amdgcn_mfma_f32_16x16x32_bf16( \
              Af[mi], Bf[QN][ni], acc[(QM)*4 + mi][(QN)*2 + ni], 0, 0, 0);       \
  __builtin_amdgcn_s_setprio(0);

  // prologue: tile 0 -> parity 0, FIFO a0,b0,b1,a1; retire a0,b0 before iter0 reads
  stage_a(0, 0, 0);
  stage_b(0, 0, 0);
  stage_b(1, 0, 0);
  stage_a(1, 0, 0);
  asm volatile("s_waitcnt vmcnt(2)" ::: "memory");
  __builtin_amdgcn_s_barrier();

  for (int t = 0; t < 32; ++t) {
    const int rp = t & 1, sp = rp ^ 1, kt = t + 1;
    const bool pf = (t < 31);
    // ---- ph0: MFMA(0,0)
    LDA(0);
    LDB(0);
    if (pf) {
      stage_a(0, sp, kt);
      asm volatile("s_waitcnt vmcnt(2)" ::: "memory");  // retires b1(t)
    } else {
      asm volatile("s_waitcnt vmcnt(0)" ::: "memory");
    }
    __builtin_amdgcn_s_barrier();
    MFMAQ(0, 0);
    // ---- ph1: MFMA(0,1)
    LDB(1);
    if (pf) {
      stage_b(0, sp, kt);
      asm volatile("s_waitcnt vmcnt(2)" ::: "memory");  // retires a1(t)
    }
    __builtin_amdgcn_s_barrier();
    MFMAQ(0, 1);
    // ---- ph2: MFMA(1,1)
    LDA(1);
    if (pf) stage_b(1, sp, kt);  // no wait needed this phase
    __builtin_amdgcn_s_barrier();
    MFMAQ(1, 1);
    // ---- ph3: MFMA(1,0) (no reads; wait covers next ph0's reads)
    if (pf) {
      stage_a(1, sp, kt);
      asm volatile("s_waitcnt vmcnt(2)" ::: "memory");  // retires a0(t+1),b0(t+1)
    }
    __builtin_amdgcn_s_barrier();
    MFMAQ(1, 0);
  }

  // epilogue: per row, (max, within-margin bitmask) over this wave's 64 h.
  // C/D frag layout: col(h) = lane&15, row-in-frag = (lane>>4)*4 + j.
  const int tile = bn * 4 + wn;  // 64-wide h-tile id (h base = bn*256 + wn*64)
#pragma unroll
  for (int m = 0; m < 8; ++m) {
    float v[4];
#pragma unroll
    for (int j = 0; j < 4; ++j)
      v[j] = fmaxf(fmaxf(acc[m][0][j], acc[m][1][j]), fmaxf(acc[m][2][j], acc[m][3][j]));
#pragma unroll
    for (int s = 1; s < 16; s <<= 1) {
#pragma unroll
      for (int j = 0; j < 4; ++j) v[j] = fmaxf(v[j], __shfl_xor(v[j], s));
    }
    unsigned long long mk[4];
#pragma unroll
    for (int j = 0; j < 4; ++j) {
      unsigned long long bmask = 0;
      const float thr = v[j] - MARGIN;
#pragma unroll
      for (int n = 0; n < 4; ++n)
        if (acc[m][n][j] >= thr) bmask |= 1ull << (n * 16 + r15);
      mk[j] = bmask;
    }
#pragma unroll
    for (int s = 1; s < 16; s <<= 1) {
#pragma unroll
      for (int j = 0; j < 4; ++j) mk[j] |= __shfl_xor(mk[j], s);
    }
    if (r15 == 0) {
#pragma unroll
      for (int j = 0; j < 4; ++j) {
        const int row = bm * 256 + wm * 128 + m * 16 + g * 4 + j;
        tmax64[(size_t)row * 64 + tile] = v[j];
        tmask64[(size_t)row * 64 + tile] = mk[j];
      }
    }
  }
}

// ---------------- phase 2: exact f64 rescore + fused gather (one wave per row) ----------
__global__ __launch_bounds__(64) void rescore_gather(const float* __restrict__ x,
                                                     const float* __restrict__ w,
                                                     const double* __restrict__ w2d,
                                                     const float* __restrict__ tmax64,
                                                     const unsigned long long* __restrict__ tmask64,
                                                     const float* __restrict__ gt,
                                                     float* __restrict__ out,
                                                     float* __restrict__ winners_f) {
  const int row = blockIdx.x;
  const int l = threadIdx.x;

  f32x4 xr[4];
  const f32x4* xp = reinterpret_cast<const f32x4*>(x + (size_t)row * D_SZ);
#pragma unroll
  for (int j = 0; j < 4; ++j) xr[j] = xp[j * 64 + l];

  const float pmax = tmax64[(size_t)row * 64 + l];
  const unsigned long long pmask = tmask64[(size_t)row * 64 + l];
  float M = pmax;
#pragma unroll
  for (int m = 1; m < 64; m <<= 1) M = fmaxf(M, __shfl_xor(M, m));
  const float thr = M - MARGIN;

  double bestS = -1e300;
  int bestI = 0x7fffffff;

  unsigned long long bits = __ballot(pmax >= thr && pmask != 0ull);
  while (bits) {
    const int src = __ffsll(bits) - 1;
    unsigned long long tmask = __shfl(pmask, src);
    const int tile = src;
    while (tmask) {
      const int b = __ffsll(tmask) - 1;
      const int h = tile * 64 + b;
      const f32x4* wp = reinterpret_cast<const f32x4*>(w + (size_t)h * D_SZ);
      double dot = 0.0;
#pragma unroll
      for (int j = 0; j < 4; ++j) {
        f32x4 wv = wp[j * 64 + l];
        dot += (double)xr[j][0] * wv[0] + (double)xr[j][1] * wv[1] +
               (double)xr[j][2] * wv[2] + (double)xr[j][3] * wv[3];
      }
#pragma unroll
      for (int m = 32; m; m >>= 1) dot += __shfl_xor(dot, m);
      const double sc = 2.0 * dot - w2d[h];  // maximize  <=>  minimize d2
      if (sc > bestS || (sc == bestS && h < bestI)) { bestS = sc; bestI = h; }
      tmask &= tmask - 1;
    }
    bits &= bits - 1;
  }

  if (l == 0) winners_f[row] = (float)bestI;
  // fused gather: out[row,:] = gt[bestI,:]  (250 f32x4, 64 lanes, 4 strided iters)
  const f32x4* gsrc = reinterpret_cast<const f32x4*>(gt + (size_t)bestI * O_SZ);
  f32x4* gdst = reinterpret_cast<f32x4*>(out + (size_t)row * O_SZ);
  for (int i = l; i < O_SZ / 4; i += 64) gdst[i] = gsrc[i];
  if (row == 0 && l == 0)
    out[(size_t)B_SZ * O_SZ + B_SZ] = (float)B_SZ;  // scalar output: x.shape[0]
}

// ---------------- phase 3a: transpose grossberg [O][H] -> GT [H][O] (post-GEMM) ---------
__global__ __launch_bounds__(256) void transpose_g(const float* __restrict__ g,
                                                   float* __restrict__ gt) {
  __shared__ float t[32][33];
  const int h0 = blockIdx.x * 32;
  const int o0 = blockIdx.y * 32;
  const int lx = threadIdx.x & 31, ly = threadIdx.x >> 5;
  for (int i = ly; i < 32; i += 8) {
    const int o = o0 + i;
    t[i][lx] = (o < O_SZ) ? g[(size_t)o * H_SZ + (h0 + lx)] : 0.f;
  }
  __syncthreads();
  for (int i = ly; i < 32; i += 8) {
    const int o = o0 + lx;
    if (o < O_SZ) gt[(size_t)(h0 + i) * O_SZ + o] = t[lx][i];
  }
}

// ---------------- launch ----------------
extern "C" void kernel_launch(void* const* d_in, const int* in_sizes, int n_in,
                              void* d_out, int out_size, void* d_ws, size_t ws_size,
                              hipStream_t stream) {
  const float* x  = (const float*)d_in[0];
  const float* kw = (const float*)d_in[1];
  const float* gw = (const float*)d_in[2];
  float* out = (float*)d_out;
  char* ws = (char*)d_ws;

  // ws layout (bytes) — max 31,522,816 (proven within ws_size):
  //   xb      @ 0          : 8192*1024*2 = 16,777,216
  //   wb      @ 16,777,216 : 4096*1024*2 =  8,388,608
  //   tmax64  @ 25,165,824 : 8192*64*4   =  2,097,152
  //   tmask64 @ 27,262,976 : 8192*64*8   =  4,194,304
  //   w2d     @ 31,457,280 : 4096*8      =     32,768
  //   gt ALIASES xb (16,384,000 <= 16,777,216): written by transpose_g AFTER the GEMM
  //   has consumed xb. This ordering invariant is load-bearing — do not hoist.
  uint16_t*           xb   = (uint16_t*)(ws);
  uint16_t*           wb   = (uint16_t*)(ws + 16777216);
  float*              tmx  = (float*)   (ws + 25165824);
  unsigned long long* tmk  = (unsigned long long*)(ws + 27262976);
  double*             w2d  = (double*)  (ws + 31457280);
  float*              gt   = (float*)   (ws);  // alias of xb

  prep<<<9216, 256, 0, stream>>>(x, xb, kw, wb, w2d);

  static bool attr_set = false;
  if (!attr_set) {
    hipFuncSetAttribute((const void*)kohonen_gemm256,
                        hipFuncAttributeMaxDynamicSharedMemorySize, 65536);
    attr_set = true;
  }
  kohonen_gemm256<<<512, 512, 65536, stream>>>(xb, wb, tmx, tmk);

  dim3 g3(H_SZ / 32, (O_SZ + 31) / 32);
  transpose_g<<<g3, 256, 0, stream>>>(gw, gt);

  rescore_gather<<<B_SZ, 64, 0, stream>>>(x, kw, w2d, tmx, tmk, gt, out,
                                          out + (size_t)B_SZ * O_SZ);
}

// Round 19
// 117.066 us; speedup vs baseline: 4.6223x; 4.6223x over previous
//
#include <hip/hip_runtime.h>
#include <stdint.h>

#define B_SZ 8192
#define D_SZ 1024
#define H_SZ 4096
#define O_SZ 1000

#define MARGIN 0.0625f

typedef float f32x4 __attribute__((ext_vector_type(4)));
typedef __bf16 bf16x8 __attribute__((ext_vector_type(8)));

// ---------------- fp32 -> bf16 (round-to-nearest-even) ----------------
static __device__ __forceinline__ uint16_t f2bf(float f) {
  uint32_t u = __float_as_uint(f);
  uint32_t r = (u + 0x7fffu + ((u >> 16) & 1u)) >> 16;
  return (uint16_t)r;
}

// ---------------- fused prep: x->bf16 | w->bf16 + w2(f64) ----------------
// blocks [0,8192)    : x convert (256 f32x4 per block)
// blocks [8192,9216) : w convert + f64 row-sumsq (4 rows/block, one WAVE per row)
__global__ __launch_bounds__(256) void prep(const float* __restrict__ x,
                                            uint16_t* __restrict__ xb,
                                            const float* __restrict__ w,
                                            uint16_t* __restrict__ wb,
                                            double* __restrict__ w2d) {
  const int bid = blockIdx.x;
  const int tid = threadIdx.x;
  if (bid < 8192) {
    const int i = bid * 256 + tid;
    f32x4 v = reinterpret_cast<const f32x4*>(x)[i];
    ushort4 o;
    o.x = f2bf(v[0]); o.y = f2bf(v[1]); o.z = f2bf(v[2]); o.w = f2bf(v[3]);
    reinterpret_cast<ushort4*>(xb)[i] = o;
  } else {
    const int h = (bid - 8192) * 4 + (tid >> 6);  // [0, 4096)
    const int l = tid & 63;
    const f32x4* wr = reinterpret_cast<const f32x4*>(w + (size_t)h * D_SZ);
    ushort4* wo = reinterpret_cast<ushort4*>(wb + (size_t)h * D_SZ);
    double s = 0.0;
#pragma unroll
    for (int j = 0; j < 4; ++j) {
      f32x4 v = wr[j * 64 + l];
      s += (double)v[0] * v[0] + (double)v[1] * v[1] + (double)v[2] * v[2] + (double)v[3] * v[3];
      ushort4 o;
      o.x = f2bf(v[0]); o.y = f2bf(v[1]); o.z = f2bf(v[2]); o.w = f2bf(v[3]);
      wo[j * 64 + l] = o;
    }
#pragma unroll
    for (int m = 32; m; m >>= 1) s += __shfl_xor(s, m);
    if (l == 0) w2d[h] = s;
  }
}

// ---------------- phase 1: 256x256 bf16 MFMA GEMM — R14 schedule (session optimum) ------
// VERIFIED (twice): 75.5 us, 910 TF, MfmaUtil 37.5%, bank-conflicts 0, absmax 0, VGPR 124.
// 8 waves (2M x 4N), per-wave C = 128x64 (8 m-frags x 4 n-frags of 16x16), BK=64.
// 24 reg-resident ds_read_b128 + 8 glds per K-tile per wave; 4 barriers, 4 counted vmcnts:
//   ph0: LDA(0)8+LDB(0)4; stage a0; vmcnt(4); bar; MFMA(0,0)
//   ph1: LDB(1)4        ; stage b0; vmcnt(4); bar; MFMA(0,1)
//   ph2: LDA(1)8        ; stage b1; vmcnt(4); bar; MFMA(1,1)
//   ph3: (no reads)     ; stage a1; vmcnt(4); bar; MFMA(1,0)
// Experiment ledger (do not repeat):
//   R9  conflict-free swizzle (read ^(r15&7)<<4, src part lp^lr)   : -7 us  KEPT
//   R10 post-MFMA barrier removal (4 bars/K-tile)                  : -6 us  KEPT
//   R11 burst-stage + 2 vmcnt/K-tile                               : +5 us  reverted
//   R15 single vmcnt(0)+barrier per K-tile                         : +2 us  reverted
//   R16 K-loop unroll x2                                           : +16 us reverted (spill)
//   R18 BK=32 + launch_bounds(512,4) for 2 blocks/CU               : +430 us reverted
//       (acc[8][4]=128 f32/lane NEEDS the 256-reg budget: 4 waves/EU halves it -> the
//        accumulator spills to scratch, 2.4 GB traffic. 2 blocks/CU is structurally
//        impossible for a 256x256/8-wave tile — occupancy 20% is arithmetic, not tuning.)
__global__ __launch_bounds__(512, 2) void kohonen_gemm256(const uint16_t* __restrict__ xb,
                                                          const uint16_t* __restrict__ wb,
                                                          float* __restrict__ tmax64,
                                                          unsigned long long* __restrict__ tmask64) {
  extern __shared__ char smem[];  // 131072 B: A slots @0, B slots @65536
  const int tid = threadIdx.x;
  const int lane = tid & 63, wid = tid >> 6;
  const int wm = wid >> 2, wn = wid & 3;
  const int r15 = lane & 15, g = lane >> 4;
  const int xorv = (r15 & 7) << 4;          // row-stripe chunk swizzle (read side)
  const int lr = lane >> 3, lp = lane & 7;  // staging: row-within-8, 16B part

  // XCD-bijective swizzle: 512 blocks = 8 XCDs x 64
  const int bid = blockIdx.x;
  const int wg = (bid & 7) * 64 + (bid >> 3);
  const int bm = wg >> 4, bn = wg & 15;

  const uint16_t* xrow = xb + (size_t)(bm * 256) * D_SZ;
  const uint16_t* wrow = wb + (size_t)(bn * 256) * D_SZ;

  f32x4 acc[8][4] = {};
  bf16x8 Af[4][2];      // current qm-half of A: [mi][ks]
  bf16x8 Bf[2][2][2];   // both qn-halves of B: [qn][ni][ks]

  auto stage_a = [&](int a, int sp, int kt) {
#pragma unroll
    for (int j = 0; j < 2; ++j) {
      const int pp = lp ^ lr;  // source chunk for row-stripe involution
      const int sr = wid * 16 + j * 8 + lr;
      const int mr = (sr < 64) ? (a * 64 + sr) : (128 + a * 64 + (sr - 64));
      const uint16_t* src = xrow + (size_t)mr * D_SZ + kt * 64 + pp * 8;
      __builtin_amdgcn_global_load_lds(
          (const __attribute__((address_space(1))) uint32_t*)src,
          (__attribute__((address_space(3))) uint32_t*)(smem + (sp * 2 + a) * 16384 +
                                                        (wid * 16 + j * 8) * 128),
          16, 0, 0);
    }
  };
  auto stage_b = [&](int b, int sp, int kt) {
#pragma unroll
    for (int j = 0; j < 2; ++j) {
      const int pp = lp ^ lr;
      const int sr = wid * 16 + j * 8 + lr;
      const int mr = (sr >> 5) * 64 + b * 32 + (sr & 31);
      const uint16_t* src = wrow + (size_t)mr * D_SZ + kt * 64 + pp * 8;
      __builtin_amdgcn_global_load_lds(
          (const __attribute__((address_space(1))) uint32_t*)src,
          (__attribute__((address_space(3))) uint32_t*)(smem + 65536 + (sp * 2 + b) * 16384 +
                                                        (wid * 16 + j * 8) * 128),
          16, 0, 0);
    }
  };

#define LDA(QM)                                                                  \
  {                                                                              \
    const char* Abq = smem + rp * 32768 + (QM)*16384;                            \
    _Pragma("unroll") for (int mi = 0; mi < 4; ++mi) {                           \
      const int sr = wm * 64 + mi * 16 + r15;                                    \
      _Pragma("unroll") for (int ks = 0; ks < 2; ++ks)                           \
          Af[mi][ks] = *reinterpret_cast<const bf16x8*>(                         \
              Abq + ((sr * 128 + ks * 64 + g * 16) ^ xorv));                     \
    }                                                                            \
  }
#define LDB(QN)                                                                  \
  {                                                                              \
    const char* Bbq = smem + 65536 + rp * 32768 + (QN)*16384;                    \
    _Pragma("unroll") for (int ni = 0; ni < 2; ++ni) {                           \
      const int sr = wn * 32 + ni * 16 + r15;                                    \
      _Pragma("unroll") for (int ks = 0; ks < 2; ++ks)                           \
          Bf[QN][ni][ks] = *reinterpret_cast<const bf16x8*>(                     \
              Bbq + ((sr * 128 + ks * 64 + g * 16) ^ xorv));                     \
    }                                                                            \
  }
#define MFMAQ(QM, QN)                                                            \
  __builtin_amdgcn_s_setprio(1);                                                 \
  _Pragma("unroll") for (int mi = 0; mi < 4; ++mi)                               \
      _Pragma("unroll") for (int ni = 0; ni < 2; ++ni)                           \
          _Pragma("unroll") for (int ks = 0; ks < 2; ++ks)                       \
              acc[(QM)*4 + mi][(QN)*2 + ni] = __builtin_amdgcn_mfma_f32_16x16x32_bf16( \
                  Af[mi][ks], Bf[QN][ni][ks], acc[(QM)*4 + mi][(QN)*2 + ni], 0, 0, 0); \
  __builtin_amdgcn_s_setprio(0);

  // prologue: tile 0 -> parity 0, order A0,B0,B1,A1; retire A0,B0 before iter0 reads
  stage_a(0, 0, 0);
  stage_b(0, 0, 0);
  stage_b(1, 0, 0);
  stage_a(1, 0, 0);
  asm volatile("s_waitcnt vmcnt(4)" ::: "memory");
  __builtin_amdgcn_s_barrier();

  for (int t = 0; t < 16; ++t) {
    const int rp = t & 1, sp = rp ^ 1, kt = t + 1;
    const bool pf = (t < 15);
    // ---- ph0: MFMA(0,0)
    LDA(0);
    LDB(0);
    if (pf) {
      stage_a(0, sp, kt);
      asm volatile("s_waitcnt vmcnt(4)" ::: "memory");
    } else {
      asm volatile("s_waitcnt vmcnt(0)" ::: "memory");
    }
    __builtin_amdgcn_s_barrier();
    MFMAQ(0, 0);
    // ---- ph1: MFMA(0,1)
    LDB(1);
    if (pf) {
      stage_b(0, sp, kt);
      asm volatile("s_waitcnt vmcnt(4)" ::: "memory");
    }
    __builtin_amdgcn_s_barrier();
    MFMAQ(0, 1);
    // ---- ph2: MFMA(1,1)
    LDA(1);
    if (pf) {
      stage_b(1, sp, kt);
      asm volatile("s_waitcnt vmcnt(4)" ::: "memory");
    }
    __builtin_amdgcn_s_barrier();
    MFMAQ(1, 1);
    // ---- ph3: MFMA(1,0) (pure register phase; vmcnt covers next ph0's reads)
    if (pf) {
      stage_a(1, sp, kt);
      asm volatile("s_waitcnt vmcnt(4)" ::: "memory");
    }
    __builtin_amdgcn_s_barrier();
    MFMAQ(1, 0);
  }

  // epilogue: per row, (max, within-margin bitmask) over this wave's 64 h.
  // C/D frag layout: col(h) = lane&15, row-in-frag = (lane>>4)*4 + j.
  const int tile = bn * 4 + wn;  // 64-wide h-tile id (h base = bn*256 + wn*64)
#pragma unroll
  for (int m = 0; m < 8; ++m) {
    float v[4];
#pragma unroll
    for (int j = 0; j < 4; ++j)
      v[j] = fmaxf(fmaxf(acc[m][0][j], acc[m][1][j]), fmaxf(acc[m][2][j], acc[m][3][j]));
#pragma unroll
    for (int s = 1; s < 16; s <<= 1) {
#pragma unroll
      for (int j = 0; j < 4; ++j) v[j] = fmaxf(v[j], __shfl_xor(v[j], s));
    }
    unsigned long long mk[4];
#pragma unroll
    for (int j = 0; j < 4; ++j) {
      unsigned long long bmask = 0;
      const float thr = v[j] - MARGIN;
#pragma unroll
      for (int n = 0; n < 4; ++n)
        if (acc[m][n][j] >= thr) bmask |= 1ull << (n * 16 + r15);
      mk[j] = bmask;
    }
#pragma unroll
    for (int s = 1; s < 16; s <<= 1) {
#pragma unroll
      for (int j = 0; j < 4; ++j) mk[j] |= __shfl_xor(mk[j], s);
    }
    if (r15 == 0) {
#pragma unroll
      for (int j = 0; j < 4; ++j) {
        const int row = bm * 256 + wm * 128 + m * 16 + g * 4 + j;
        tmax64[(size_t)row * 64 + tile] = v[j];
        tmask64[(size_t)row * 64 + tile] = mk[j];
      }
    }
  }
}

// ---------------- phase 2: exact f64 rescore + fused gather (one wave per row) ----------
__global__ __launch_bounds__(64) void rescore_gather(const float* __restrict__ x,
                                                     const float* __restrict__ w,
                                                     const double* __restrict__ w2d,
                                                     const float* __restrict__ tmax64,
                                                     const unsigned long long* __restrict__ tmask64,
                                                     const float* __restrict__ gt,
                                                     float* __restrict__ out,
                                                     float* __restrict__ winners_f) {
  const int row = blockIdx.x;
  const int l = threadIdx.x;

  f32x4 xr[4];
  const f32x4* xp = reinterpret_cast<const f32x4*>(x + (size_t)row * D_SZ);
#pragma unroll
  for (int j = 0; j < 4; ++j) xr[j] = xp[j * 64 + l];

  const float pmax = tmax64[(size_t)row * 64 + l];
  const unsigned long long pmask = tmask64[(size_t)row * 64 + l];
  float M = pmax;
#pragma unroll
  for (int m = 1; m < 64; m <<= 1) M = fmaxf(M, __shfl_xor(M, m));
  const float thr = M - MARGIN;

  double bestS = -1e300;
  int bestI = 0x7fffffff;

  unsigned long long bits = __ballot(pmax >= thr && pmask != 0ull);
  while (bits) {
    const int src = __ffsll(bits) - 1;
    unsigned long long tmask = __shfl(pmask, src);
    const int tile = src;
    while (tmask) {
      const int b = __ffsll(tmask) - 1;
      const int h = tile * 64 + b;
      const f32x4* wp = reinterpret_cast<const f32x4*>(w + (size_t)h * D_SZ);
      double dot = 0.0;
#pragma unroll
      for (int j = 0; j < 4; ++j) {
        f32x4 wv = wp[j * 64 + l];
        dot += (double)xr[j][0] * wv[0] + (double)xr[j][1] * wv[1] +
               (double)xr[j][2] * wv[2] + (double)xr[j][3] * wv[3];
      }
#pragma unroll
      for (int m = 32; m; m >>= 1) dot += __shfl_xor(dot, m);
      const double sc = 2.0 * dot - w2d[h];  // maximize  <=>  minimize d2
      if (sc > bestS || (sc == bestS && h < bestI)) { bestS = sc; bestI = h; }
      tmask &= tmask - 1;
    }
    bits &= bits - 1;
  }

  if (l == 0) winners_f[row] = (float)bestI;
  // fused gather: out[row,:] = gt[bestI,:]  (250 f32x4, 64 lanes, 4 strided iters)
  const f32x4* gsrc = reinterpret_cast<const f32x4*>(gt + (size_t)bestI * O_SZ);
  f32x4* gdst = reinterpret_cast<f32x4*>(out + (size_t)row * O_SZ);
  for (int i = l; i < O_SZ / 4; i += 64) gdst[i] = gsrc[i];
  if (row == 0 && l == 0)
    out[(size_t)B_SZ * O_SZ + B_SZ] = (float)B_SZ;  // scalar output: x.shape[0]
}

// ---------------- phase 3a: transpose grossberg [O][H] -> GT [H][O] (post-GEMM) ---------
__global__ __launch_bounds__(256) void transpose_g(const float* __restrict__ g,
                                                   float* __restrict__ gt) {
  __shared__ float t[32][33];
  const int h0 = blockIdx.x * 32;
  const int o0 = blockIdx.y * 32;
  const int lx = threadIdx.x & 31, ly = threadIdx.x >> 5;
  for (int i = ly; i < 32; i += 8) {
    const int o = o0 + i;
    t[i][lx] = (o < O_SZ) ? g[(size_t)o * H_SZ + (h0 + lx)] : 0.f;
  }
  __syncthreads();
  for (int i = ly; i < 32; i += 8) {
    const int o = o0 + lx;
    if (o < O_SZ) gt[(size_t)(h0 + i) * O_SZ + o] = t[lx][i];
  }
}

// ---------------- launch ----------------
extern "C" void kernel_launch(void* const* d_in, const int* in_sizes, int n_in,
                              void* d_out, int out_size, void* d_ws, size_t ws_size,
                              hipStream_t stream) {
  const float* x  = (const float*)d_in[0];
  const float* kw = (const float*)d_in[1];
  const float* gw = (const float*)d_in[2];
  float* out = (float*)d_out;
  char* ws = (char*)d_ws;

  // ws layout (bytes) — max 31,522,816 (proven within ws_size):
  //   xb      @ 0          : 8192*1024*2 = 16,777,216
  //   wb      @ 16,777,216 : 4096*1024*2 =  8,388,608
  //   tmax64  @ 25,165,824 : 8192*64*4   =  2,097,152
  //   tmask64 @ 27,262,976 : 8192*64*8   =  4,194,304
  //   w2d     @ 31,457,280 : 4096*8      =     32,768
  //   gt ALIASES xb (16,384,000 <= 16,777,216): written by transpose_g AFTER the GEMM
  //   has consumed xb. This ordering invariant is load-bearing — do not hoist.
  uint16_t*           xb   = (uint16_t*)(ws);
  uint16_t*           wb   = (uint16_t*)(ws + 16777216);
  float*              tmx  = (float*)   (ws + 25165824);
  unsigned long long* tmk  = (unsigned long long*)(ws + 27262976);
  double*             w2d  = (double*)  (ws + 31457280);
  float*              gt   = (float*)   (ws);  // alias of xb

  prep<<<9216, 256, 0, stream>>>(x, xb, kw, wb, w2d);

  static bool attr_set = false;
  if (!attr_set) {
    hipFuncSetAttribute((const void*)kohonen_gemm256,
                        hipFuncAttributeMaxDynamicSharedMemorySize, 131072);
    attr_set = true;
  }
  kohonen_gemm256<<<512, 512, 131072, stream>>>(xb, wb, tmx, tmk);

  dim3 g3(H_SZ / 32, (O_SZ + 31) / 32);
  transpose_g<<<g3, 256, 0, stream>>>(gw, gt);

  rescore_gather<<<B_SZ, 64, 0, stream>>>(x, kw, w2d, tmx, tmk, gt, out,
                                          out + (size_t)B_SZ * O_SZ);
}